// Round 1
// baseline (1783.220 us; speedup 1.0000x reference)
//
#include <hip/hip_runtime.h>

// Problem constants
#define E_TOT 8192
#define NB    32
#define H     128

// ---------------------------------------------------------------------------
// Fused NNConv edge kernel:
//   msg[e,o] = sum_{d<33} sum_{i<CIN} ea'[e,d] * x[src[e],i] * W[d,i,o]
// where ea'[:,32]=1 and W[32,i,o]=nn_b[i*128+o], W[d,i,o]=nn_w[d, i*128+o].
// Atomically adds msg into agg[dst]. Invalid edges (src==-1) are skipped.
// Block: 64 edges x 128 outputs, 256 threads (each thread: 1 edge, 32 outputs).
// K-dim (d) split over blockIdx.y (4 chunks) for grid occupancy.
// ---------------------------------------------------------------------------
template<int CIN>
__global__ __launch_bounds__(256)
void conv_edge(const float* __restrict__ xin,
               const float* __restrict__ ea,     // [E,32]
               const int*   __restrict__ esrc,   // [E], -1 = invalid
               const int*   __restrict__ edst,   // [E]
               const float* __restrict__ nnw,    // [32, CIN*128]
               const float* __restrict__ nnb,    // [CIN*128]
               float*       __restrict__ agg)    // [n,128]
{
    __shared__ float xs[64][CIN + 1];   // +1 pad: 2-way LDS aliasing only (free)
    __shared__ float eas[64][33];
    __shared__ int   sdst[64];
    __shared__ int   ssrc[64];

    const int tid = threadIdx.x;
    const int e0  = blockIdx.x * 64;

    for (int idx = tid; idx < 64 * 32; idx += 256) {
        int el = idx >> 5, d = idx & 31;
        eas[el][d] = ea[(e0 + el) * 32 + d];
    }
    if (tid < 64) {
        eas[tid][32] = 1.0f;                 // bias row
        int s = esrc[e0 + tid];
        ssrc[tid] = (s >= 0) ? s : 0;
        sdst[tid] = (s >= 0) ? edst[e0 + tid] : -1;
    }
    __syncthreads();

    constexpr int C4 = CIN / 4;
    for (int idx = tid; idx < 64 * C4; idx += 256) {
        int el = idx / C4, c4 = idx % C4;
        const float4 v = reinterpret_cast<const float4*>(xin + (size_t)ssrc[el] * CIN)[c4];
        xs[el][c4 * 4 + 0] = v.x; xs[el][c4 * 4 + 1] = v.y;
        xs[el][c4 * 4 + 2] = v.z; xs[el][c4 * 4 + 3] = v.w;
    }
    __syncthreads();

    const int el    = tid & 63;
    const int oc    = tid >> 6;     // 0..3
    const int obase = oc * 32;

    float acc[32];
    #pragma unroll
    for (int j = 0; j < 32; ++j) acc[j] = 0.0f;

    const int dsplit[5] = {0, 9, 17, 25, 33};
    const int dlo = dsplit[blockIdx.y];
    const int dhi = dsplit[blockIdx.y + 1];

    for (int d = dlo; d < dhi; ++d) {
        const float* wrow  = (d < 32) ? (nnw + (size_t)d * CIN * H) : nnb;
        const float* wbase = wrow + obase;
        const float  sc    = eas[el][d];
        for (int i = 0; i < CIN; ++i) {
            const float a = sc * xs[el][i];
            const float4* w4 = reinterpret_cast<const float4*>(wbase + i * H);
            #pragma unroll
            for (int j4 = 0; j4 < 8; ++j4) {
                float4 wv = w4[j4];
                acc[j4 * 4 + 0] += a * wv.x;
                acc[j4 * 4 + 1] += a * wv.y;
                acc[j4 * 4 + 2] += a * wv.z;
                acc[j4 * 4 + 3] += a * wv.w;
            }
        }
    }

    const int dst = sdst[el];
    if (dst >= 0) {
        float* out = agg + (size_t)dst * H + obase;
        #pragma unroll
        for (int j = 0; j < 32; ++j) atomicAdd(out + j, acc[j]);
    }
}

// agg_init[v,o] = bias[o] + sum_i x[v,i]*root[i,o]
template<int CIN>
__global__ __launch_bounds__(128)
void node_root(const float* __restrict__ x, const float* __restrict__ root,
               const float* __restrict__ bias, float* __restrict__ out)
{
    const int v = blockIdx.x;
    const int tid = threadIdx.x;   // = output column o
    __shared__ float xsh[CIN];
    for (int i = tid; i < CIN; i += 128) xsh[i] = x[(size_t)v * CIN + i];
    __syncthreads();
    float acc = bias[tid];
    for (int i = 0; i < CIN; ++i) acc += xsh[i] * root[i * H + tid];
    out[(size_t)v * H + tid] = acc;
}

// Column sums / sumsq over n rows, atomically accumulated into gsum/gsumsq.
__global__ __launch_bounds__(256)
void bn_stats(const float* __restrict__ h, int n,
              float* __restrict__ gsum, float* __restrict__ gsumsq)
{
    const int tid   = threadIdx.x;
    const int col   = tid & 127;
    const int rhalf = tid >> 7;   // 0/1
    float s = 0.f, sq = 0.f;
    for (int r = blockIdx.x * 2 + rhalf; r < n; r += gridDim.x * 2) {
        float v = h[(size_t)r * H + col];
        s += v; sq += v * v;
    }
    __shared__ float sh[256];
    sh[tid] = s;  __syncthreads();
    if (rhalf == 0) s += sh[tid + 128];
    __syncthreads();
    sh[tid] = sq; __syncthreads();
    if (rhalf == 0) {
        sq += sh[tid + 128];
        atomicAdd(&gsum[col], s);
        atomicAdd(&gsumsq[col], sq);
    }
}

// y = relu(gamma*(x-mu)*rsqrt(var+eps)+beta) in place; score[r]=tanh((y.pw)*invnorm)
__global__ __launch_bounds__(128)
void bn_apply_score(float* __restrict__ h, float n_f,
                    const float* __restrict__ gsum, const float* __restrict__ gsumsq,
                    const float* __restrict__ gamma, const float* __restrict__ beta,
                    const float* __restrict__ pw, const float* __restrict__ invn,
                    int invn_idx, float* __restrict__ score)
{
    const int r = blockIdx.x, c = threadIdx.x;
    const float mu  = gsum[c] / n_f;
    const float var = gsumsq[c] / n_f - mu * mu;
    float y = gamma[c] * (h[(size_t)r * H + c] - mu) * rsqrtf(var + 1e-5f) + beta[c];
    y = fmaxf(y, 0.f);
    h[(size_t)r * H + c] = y;
    __shared__ float sh[128];
    sh[c] = y * pw[c];
    __syncthreads();
    for (int off = 64; off > 0; off >>= 1) {
        if (c < off) sh[c] += sh[c + off];
        __syncthreads();
    }
    if (c == 0) score[r] = tanhf(sh[0] * invn[invn_idx]);
}

// invn[s] = 1/||pw_s||
__global__ __launch_bounds__(128)
void invnorm_kernel(const float* __restrict__ pw1, const float* __restrict__ pw2,
                    const float* __restrict__ pw3, float* __restrict__ invn)
{
    __shared__ float sh[128];
    const int tid = threadIdx.x;
    for (int s = 0; s < 3; ++s) {
        const float* pw = (s == 0) ? pw1 : ((s == 1) ? pw2 : pw3);
        float v = pw[tid];
        sh[tid] = v * v;
        __syncthreads();
        for (int off = 64; off > 0; off >>= 1) {
            if (tid < off) sh[tid] += sh[tid + off];
            __syncthreads();
        }
        if (tid == 0) invn[s] = rsqrtf(sh[0]);
        __syncthreads();
    }
}

// Per-graph top-k by rank; new id = rank (within-graph permutation is
// irrelevant downstream — BN/scatter/mean are row-permutation-invariant).
__global__ __launch_bounds__(128)
void pool_kernel(const float* __restrict__ h, const float* __restrict__ score,
                 int npg, int k, float* __restrict__ xnew, int* __restrict__ mapping)
{
    const int g = blockIdx.x;
    const int tid = threadIdx.x;
    __shared__ float s_ld[128];
    __shared__ int   rank_ld[128];
    if (tid < npg) s_ld[tid] = score[g * npg + tid];
    __syncthreads();
    if (tid < npg) {
        const float si = s_ld[tid];
        int cnt = 0;
        for (int j = 0; j < npg; ++j) {
            float sj = s_ld[j];
            cnt += (sj > si) || (sj == si && j < tid);
        }
        rank_ld[tid] = cnt;
        mapping[g * npg + tid] = (cnt < k) ? (g * k + cnt) : -1;
    }
    __syncthreads();
    for (int i = 0; i < npg; ++i) {
        const int r = rank_ld[i];
        if (r < k) {
            const float sc = s_ld[i];
            for (int c = tid; c < H; c += 128)
                xnew[(size_t)(g * k + r) * H + c] = h[(size_t)(g * npg + i) * H + c] * sc;
        }
    }
}

// Propagate edge endpoints through a pooling mapping; -1 marks invalid.
__global__ __launch_bounds__(256)
void remap_edges(const int* __restrict__ osrc, const int* __restrict__ odst,
                 const int* __restrict__ mapping,
                 int* __restrict__ nsrc, int* __restrict__ ndst)
{
    const int e = blockIdx.x * 256 + threadIdx.x;
    if (e >= E_TOT) return;
    const int s = osrc[e];
    int ns = -1, nd = -1;
    if (s >= 0) {
        int ms = mapping[s];
        int md = mapping[odst[e]];
        if (ms >= 0 && md >= 0) { ns = ms; nd = md; }
    }
    nsrc[e] = ns; ndst[e] = nd;
}

// mean over 16 rows -> lin1(128->64)+relu -> lin2(64->1)+sigmoid
__global__ __launch_bounds__(128)
void final_kernel(const float* __restrict__ x4,      // [32*16,128]
                  const float* __restrict__ lin1_w,  // [128,64]
                  const float* __restrict__ lin1_b,  // [64]
                  const float* __restrict__ lin2_w,  // [64,1]
                  const float* __restrict__ lin2_b,  // [1]
                  float* __restrict__ out)           // [32]
{
    const int g = blockIdx.x;
    const int tid = threadIdx.x;
    __shared__ float gmean[128];
    __shared__ float h1[64];
    float s = 0.f;
    for (int r = 0; r < 16; ++r) s += x4[(size_t)(g * 16 + r) * H + tid];
    gmean[tid] = s * (1.0f / 16.0f);
    __syncthreads();
    if (tid < 64) {
        float acc = lin1_b[tid];
        for (int o = 0; o < 128; ++o) acc += gmean[o] * lin1_w[o * 64 + tid];
        h1[tid] = fmaxf(acc, 0.f);
    }
    __syncthreads();
    if (tid == 0) {
        float z = lin2_b[0];
        for (int j = 0; j < 64; ++j) z += h1[j] * lin2_w[j];
        out[g] = 1.0f / (1.0f + expf(-z));
    }
}

extern "C" void kernel_launch(void* const* d_in, const int* in_sizes, int n_in,
                              void* d_out, int out_size, void* d_ws, size_t ws_size,
                              hipStream_t stream)
{
    // Inputs in setup_inputs() dict order
    const float* x        = (const float*)d_in[0];   // [4096,64]
    const int*   ei       = (const int*)  d_in[1];   // [2,8192]
    const float* eattr    = (const float*)d_in[2];   // [8192,32]
    // d_in[3] = batch (unused; graphs are contiguous blocks)
    const float* nn1_w    = (const float*)d_in[4];
    const float* nn1_b    = (const float*)d_in[5];
    const float* root1    = (const float*)d_in[6];
    const float* bias1    = (const float*)d_in[7];
    const float* nn2_w    = (const float*)d_in[8];
    const float* nn2_b    = (const float*)d_in[9];
    const float* root2    = (const float*)d_in[10];
    const float* bias2    = (const float*)d_in[11];
    const float* nn3_w    = (const float*)d_in[12];
    const float* nn3_b    = (const float*)d_in[13];
    const float* root3    = (const float*)d_in[14];
    const float* bias3    = (const float*)d_in[15];
    const float* gamma1   = (const float*)d_in[16];
    const float* beta1    = (const float*)d_in[17];
    const float* gamma2   = (const float*)d_in[18];
    const float* beta2    = (const float*)d_in[19];
    const float* gamma3   = (const float*)d_in[20];
    const float* beta3    = (const float*)d_in[21];
    const float* pw1      = (const float*)d_in[22];
    const float* pw2      = (const float*)d_in[23];
    const float* pw3      = (const float*)d_in[24];
    const float* lin1_w   = (const float*)d_in[25];
    const float* lin1_b   = (const float*)d_in[26];
    const float* lin2_w   = (const float*)d_in[27];
    const float* lin2_b   = (const float*)d_in[28];

    const int* ei_src = ei;
    const int* ei_dst = ei + E_TOT;

    // Workspace carve (256B-aligned chunks)
    char* wp = (char*)d_ws;
    auto alloc = [&](size_t bytes) { char* p = wp; wp += (bytes + 255) & ~(size_t)255; return p; };
    float* h1     = (float*)alloc(4096 * 128 * 4);
    float* x2     = (float*)alloc(2048 * 128 * 4);
    float* h2     = (float*)alloc(2048 * 128 * 4);
    float* x3     = (float*)alloc(1024 * 128 * 4);
    float* h3     = (float*)alloc(1024 * 128 * 4);
    float* x4     = (float*)alloc(512 * 128 * 4);
    float* score1 = (float*)alloc(4096 * 4);
    float* score2 = (float*)alloc(2048 * 4);
    float* score3 = (float*)alloc(1024 * 4);
    int*   map1   = (int*)alloc(4096 * 4);
    int*   map2   = (int*)alloc(2048 * 4);
    int*   map3   = (int*)alloc(1024 * 4);
    int*   src1   = (int*)alloc(E_TOT * 4);
    int*   dst1   = (int*)alloc(E_TOT * 4);
    int*   src2   = (int*)alloc(E_TOT * 4);
    int*   dst2   = (int*)alloc(E_TOT * 4);
    float* stats  = (float*)alloc(6 * 128 * 4);   // gsum1,gsq1,gsum2,gsq2,gsum3,gsq3
    float* invn   = (float*)alloc(16);

    hipMemsetAsync(stats, 0, 6 * 128 * sizeof(float), stream);
    invnorm_kernel<<<1, 128, 0, stream>>>(pw1, pw2, pw3, invn);

    // ---- Stage 1: NNConv(64->128) + BN + ReLU + TopK(128->64) ----
    node_root<64><<<4096, 128, 0, stream>>>(x, root1, bias1, h1);
    conv_edge<64><<<dim3(E_TOT / 64, 4), 256, 0, stream>>>(x, eattr, ei_src, ei_dst,
                                                           nn1_w, nn1_b, h1);
    bn_stats<<<64, 256, 0, stream>>>(h1, 4096, stats, stats + 128);
    bn_apply_score<<<4096, 128, 0, stream>>>(h1, 4096.0f, stats, stats + 128,
                                             gamma1, beta1, pw1, invn, 0, score1);
    pool_kernel<<<NB, 128, 0, stream>>>(h1, score1, 128, 64, x2, map1);
    remap_edges<<<E_TOT / 256, 256, 0, stream>>>(ei_src, ei_dst, map1, src1, dst1);

    // ---- Stage 2: NNConv(128->128) + BN + ReLU + TopK(64->32) ----
    node_root<128><<<2048, 128, 0, stream>>>(x2, root2, bias2, h2);
    conv_edge<128><<<dim3(E_TOT / 64, 4), 256, 0, stream>>>(x2, eattr, src1, dst1,
                                                            nn2_w, nn2_b, h2);
    bn_stats<<<64, 256, 0, stream>>>(h2, 2048, stats + 256, stats + 384);
    bn_apply_score<<<2048, 128, 0, stream>>>(h2, 2048.0f, stats + 256, stats + 384,
                                             gamma2, beta2, pw2, invn, 1, score2);
    pool_kernel<<<NB, 128, 0, stream>>>(h2, score2, 64, 32, x3, map2);
    remap_edges<<<E_TOT / 256, 256, 0, stream>>>(src1, dst1, map2, src2, dst2);

    // ---- Stage 3: NNConv(128->128) + BN + ReLU + TopK(32->16) ----
    node_root<128><<<1024, 128, 0, stream>>>(x3, root3, bias3, h3);
    conv_edge<128><<<dim3(E_TOT / 64, 4), 256, 0, stream>>>(x3, eattr, src2, dst2,
                                                            nn3_w, nn3_b, h3);
    bn_stats<<<64, 256, 0, stream>>>(h3, 1024, stats + 512, stats + 640);
    bn_apply_score<<<1024, 128, 0, stream>>>(h3, 1024.0f, stats + 512, stats + 640,
                                             gamma3, beta3, pw3, invn, 2, score3);
    pool_kernel<<<NB, 128, 0, stream>>>(h3, score3, 32, 16, x4, map3);

    // ---- Readout ----
    final_kernel<<<NB, 128, 0, stream>>>(x4, lin1_w, lin1_b, lin2_w, lin2_b, (float*)d_out);
}

// Round 2
// 447.115 us; speedup vs baseline: 3.9883x; 3.9883x over previous
//
#include <hip/hip_runtime.h>

// Problem constants
#define E_TOT 8192
#define NB    32
#define H     128
#define ND    33      // 32 edge-attr dims + 1 bias row

// ---------------------------------------------------------------------------
// ygemm: Y[v, dd, o] = sum_i x[v,i] * W[d0+dd, i, o]   (dd in [0,nd))
// where W[d] = nn_w row d for d<32, nn_b for d==32.
// Block: 128 nodes x 128 outputs (one d per blockIdx.y), 256 threads,
// each thread 8x8 outputs in registers; K staged through LDS in chunks of 16.
// ---------------------------------------------------------------------------
template<int CIN>
__global__ __launch_bounds__(256)
void ygemm(const float* __restrict__ x,    // [nv, CIN]
           const float* __restrict__ nnw,  // [32, CIN*128]
           const float* __restrict__ nnb,  // [CIN*128]
           int d0,
           float* __restrict__ Y,          // [nv, nd, 128]
           int nd)
{
    const int v0 = blockIdx.x * 128;
    const int gd = d0 + blockIdx.y;
    const float* __restrict__ W = (gd < 32) ? (nnw + (size_t)gd * CIN * H) : nnb;

    __shared__ float Xt[16][132];   // [k][v], +4 pad -> 2-way bank aliasing only
    __shared__ float Wd[16][132];   // [k][o]

    const int tx = threadIdx.x & 15;   // col group: outputs tx*8..tx*8+7
    const int ty = threadIdx.x >> 4;   // row group: nodes  ty*8..ty*8+7

    float acc[8][8];
    #pragma unroll
    for (int r = 0; r < 8; ++r)
        #pragma unroll
        for (int c = 0; c < 8; ++c) acc[r][c] = 0.0f;

    for (int k0 = 0; k0 < CIN; k0 += 16) {
        // stage X^T chunk: Xt[k][v] = x[v0+v][k0+k]
        for (int idx = threadIdx.x; idx < 128 * 16; idx += 256) {
            const int v = idx >> 4, k = idx & 15;
            Xt[k][v] = x[(size_t)(v0 + v) * CIN + k0 + k];
        }
        // stage W chunk: Wd[k][o] = W[(k0+k)*128 + o], float4 coalesced
        for (int idx = threadIdx.x; idx < 32 * 16; idx += 256) {
            const int k = idx >> 5, f4 = idx & 31;
            const float4 w = reinterpret_cast<const float4*>(W + (size_t)(k0 + k) * H)[f4];
            *reinterpret_cast<float4*>(&Wd[k][f4 * 4]) = w;
        }
        __syncthreads();

        #pragma unroll
        for (int k = 0; k < 16; ++k) {
            float a[8], b[8];
            *reinterpret_cast<float4*>(&a[0]) = *reinterpret_cast<const float4*>(&Xt[k][ty * 8]);
            *reinterpret_cast<float4*>(&a[4]) = *reinterpret_cast<const float4*>(&Xt[k][ty * 8 + 4]);
            *reinterpret_cast<float4*>(&b[0]) = *reinterpret_cast<const float4*>(&Wd[k][tx * 8]);
            *reinterpret_cast<float4*>(&b[4]) = *reinterpret_cast<const float4*>(&Wd[k][tx * 8 + 4]);
            #pragma unroll
            for (int r = 0; r < 8; ++r)
                #pragma unroll
                for (int c = 0; c < 8; ++c) acc[r][c] += a[r] * b[c];
        }
        __syncthreads();
    }

    // write out: Y[v0+ty*8+r][blockIdx.y][tx*8 + 0..7]
    const size_t orow = (size_t)blockIdx.y * H + tx * 8;
    #pragma unroll
    for (int r = 0; r < 8; ++r) {
        float* out = Y + ((size_t)(v0 + ty * 8 + r) * nd) * H + orow;
        *reinterpret_cast<float4*>(out)     = *reinterpret_cast<float4*>(&acc[r][0]);
        *reinterpret_cast<float4*>(out + 4) = *reinterpret_cast<float4*>(&acc[r][4]);
    }
}

// ---------------------------------------------------------------------------
// contract_edges: agg[dst[e], :] += sum_dd ea'[e, d0+dd] * Y[src[e], dd, :]
// One wave per edge; lane covers 2 output columns (float2, 512B coalesced rows).
// ---------------------------------------------------------------------------
__global__ __launch_bounds__(256)
void contract_edges(const float* __restrict__ Y,    // [nv, nd, 128]
                    const float* __restrict__ ea,   // [E, 32]
                    const int*   __restrict__ esrc, // [E], -1 invalid
                    const int*   __restrict__ edst,
                    int nd, int d0,
                    float*       __restrict__ agg)  // [n, 128]
{
    const int wave = threadIdx.x >> 6;
    const int lane = threadIdx.x & 63;
    const int e = blockIdx.x * 4 + wave;
    const int s = esrc[e];
    if (s < 0) return;

    const float* ybase = Y + (size_t)s * nd * H + lane * 2;
    float ax = 0.f, ay = 0.f;
    #pragma unroll 4
    for (int dd = 0; dd < nd; ++dd) {
        const int gd = d0 + dd;
        const float c = (gd < 32) ? ea[(size_t)e * 32 + gd] : 1.0f;
        const float2 y = *reinterpret_cast<const float2*>(ybase + (size_t)dd * H);
        ax += c * y.x;
        ay += c * y.y;
    }
    float* out = agg + (size_t)edst[e] * H + lane * 2;
    atomicAdd(out, ax);
    atomicAdd(out + 1, ay);
}

// agg_init[v,o] = bias[o] + sum_i x[v,i]*root[i,o]
template<int CIN>
__global__ __launch_bounds__(128)
void node_root(const float* __restrict__ x, const float* __restrict__ root,
               const float* __restrict__ bias, float* __restrict__ out)
{
    const int v = blockIdx.x;
    const int tid = threadIdx.x;   // = output column o
    __shared__ float xsh[CIN];
    for (int i = tid; i < CIN; i += 128) xsh[i] = x[(size_t)v * CIN + i];
    __syncthreads();
    float acc = bias[tid];
    for (int i = 0; i < CIN; ++i) acc += xsh[i] * root[i * H + tid];
    out[(size_t)v * H + tid] = acc;
}

// Column sums / sumsq over n rows, atomically accumulated into gsum/gsumsq.
__global__ __launch_bounds__(256)
void bn_stats(const float* __restrict__ h, int n,
              float* __restrict__ gsum, float* __restrict__ gsumsq)
{
    const int tid   = threadIdx.x;
    const int col   = tid & 127;
    const int rhalf = tid >> 7;
    float s = 0.f, sq = 0.f;
    for (int r = blockIdx.x * 2 + rhalf; r < n; r += gridDim.x * 2) {
        float v = h[(size_t)r * H + col];
        s += v; sq += v * v;
    }
    __shared__ float sh[256];
    sh[tid] = s;  __syncthreads();
    if (rhalf == 0) s += sh[tid + 128];
    __syncthreads();
    sh[tid] = sq; __syncthreads();
    if (rhalf == 0) {
        sq += sh[tid + 128];
        atomicAdd(&gsum[col], s);
        atomicAdd(&gsumsq[col], sq);
    }
}

// y = relu(gamma*(x-mu)*rsqrt(var+eps)+beta) in place; score[r]=tanh((y.pw)*invnorm)
__global__ __launch_bounds__(128)
void bn_apply_score(float* __restrict__ h, float n_f,
                    const float* __restrict__ gsum, const float* __restrict__ gsumsq,
                    const float* __restrict__ gamma, const float* __restrict__ beta,
                    const float* __restrict__ pw, const float* __restrict__ invn,
                    int invn_idx, float* __restrict__ score)
{
    const int r = blockIdx.x, c = threadIdx.x;
    const float mu  = gsum[c] / n_f;
    const float var = gsumsq[c] / n_f - mu * mu;
    float y = gamma[c] * (h[(size_t)r * H + c] - mu) * rsqrtf(var + 1e-5f) + beta[c];
    y = fmaxf(y, 0.f);
    h[(size_t)r * H + c] = y;
    __shared__ float sh[128];
    sh[c] = y * pw[c];
    __syncthreads();
    for (int off = 64; off > 0; off >>= 1) {
        if (c < off) sh[c] += sh[c + off];
        __syncthreads();
    }
    if (c == 0) score[r] = tanhf(sh[0] * invn[invn_idx]);
}

// invn[s] = 1/||pw_s||
__global__ __launch_bounds__(128)
void invnorm_kernel(const float* __restrict__ pw1, const float* __restrict__ pw2,
                    const float* __restrict__ pw3, float* __restrict__ invn)
{
    __shared__ float sh[128];
    const int tid = threadIdx.x;
    for (int s = 0; s < 3; ++s) {
        const float* pw = (s == 0) ? pw1 : ((s == 1) ? pw2 : pw3);
        float v = pw[tid];
        sh[tid] = v * v;
        __syncthreads();
        for (int off = 64; off > 0; off >>= 1) {
            if (tid < off) sh[tid] += sh[tid + off];
            __syncthreads();
        }
        if (tid == 0) invn[s] = rsqrtf(sh[0]);
        __syncthreads();
    }
}

// Per-graph top-k by rank; new id = rank (within-graph permutation is
// irrelevant downstream — BN/scatter/mean are row-permutation-invariant).
__global__ __launch_bounds__(128)
void pool_kernel(const float* __restrict__ h, const float* __restrict__ score,
                 int npg, int k, float* __restrict__ xnew, int* __restrict__ mapping)
{
    const int g = blockIdx.x;
    const int tid = threadIdx.x;
    __shared__ float s_ld[128];
    __shared__ int   rank_ld[128];
    if (tid < npg) s_ld[tid] = score[g * npg + tid];
    __syncthreads();
    if (tid < npg) {
        const float si = s_ld[tid];
        int cnt = 0;
        for (int j = 0; j < npg; ++j) {
            float sj = s_ld[j];
            cnt += (sj > si) || (sj == si && j < tid);
        }
        rank_ld[tid] = cnt;
        mapping[g * npg + tid] = (cnt < k) ? (g * k + cnt) : -1;
    }
    __syncthreads();
    for (int i = 0; i < npg; ++i) {
        const int r = rank_ld[i];
        if (r < k) {
            const float sc = s_ld[i];
            for (int c = tid; c < H; c += 128)
                xnew[(size_t)(g * k + r) * H + c] = h[(size_t)(g * npg + i) * H + c] * sc;
        }
    }
}

// Propagate edge endpoints through a pooling mapping; -1 marks invalid.
__global__ __launch_bounds__(256)
void remap_edges(const int* __restrict__ osrc, const int* __restrict__ odst,
                 const int* __restrict__ mapping,
                 int* __restrict__ nsrc, int* __restrict__ ndst)
{
    const int e = blockIdx.x * 256 + threadIdx.x;
    if (e >= E_TOT) return;
    const int s = osrc[e];
    int ns = -1, nd = -1;
    if (s >= 0) {
        int ms = mapping[s];
        int md = mapping[odst[e]];
        if (ms >= 0 && md >= 0) { ns = ms; nd = md; }
    }
    nsrc[e] = ns; ndst[e] = nd;
}

// mean over 16 rows -> lin1(128->64)+relu -> lin2(64->1)+sigmoid
__global__ __launch_bounds__(128)
void final_kernel(const float* __restrict__ x4,      // [32*16,128]
                  const float* __restrict__ lin1_w,  // [128,64]
                  const float* __restrict__ lin1_b,  // [64]
                  const float* __restrict__ lin2_w,  // [64,1]
                  const float* __restrict__ lin2_b,  // [1]
                  float* __restrict__ out)           // [32]
{
    const int g = blockIdx.x;
    const int tid = threadIdx.x;
    __shared__ float gmean[128];
    __shared__ float h1[64];
    float s = 0.f;
    for (int r = 0; r < 16; ++r) s += x4[(size_t)(g * 16 + r) * H + tid];
    gmean[tid] = s * (1.0f / 16.0f);
    __syncthreads();
    if (tid < 64) {
        float acc = lin1_b[tid];
        for (int o = 0; o < 128; ++o) acc += gmean[o] * lin1_w[o * 64 + tid];
        h1[tid] = fmaxf(acc, 0.f);
    }
    __syncthreads();
    if (tid == 0) {
        float z = lin2_b[0];
        for (int j = 0; j < 64; ++j) z += h1[j] * lin2_w[j];
        out[g] = 1.0f / (1.0f + expf(-z));
    }
}

extern "C" void kernel_launch(void* const* d_in, const int* in_sizes, int n_in,
                              void* d_out, int out_size, void* d_ws, size_t ws_size,
                              hipStream_t stream)
{
    const float* x        = (const float*)d_in[0];   // [4096,64]
    const int*   ei       = (const int*)  d_in[1];   // [2,8192]
    const float* eattr    = (const float*)d_in[2];   // [8192,32]
    const float* nn1_w    = (const float*)d_in[4];
    const float* nn1_b    = (const float*)d_in[5];
    const float* root1    = (const float*)d_in[6];
    const float* bias1    = (const float*)d_in[7];
    const float* nn2_w    = (const float*)d_in[8];
    const float* nn2_b    = (const float*)d_in[9];
    const float* root2    = (const float*)d_in[10];
    const float* bias2    = (const float*)d_in[11];
    const float* nn3_w    = (const float*)d_in[12];
    const float* nn3_b    = (const float*)d_in[13];
    const float* root3    = (const float*)d_in[14];
    const float* bias3    = (const float*)d_in[15];
    const float* gamma1   = (const float*)d_in[16];
    const float* beta1    = (const float*)d_in[17];
    const float* gamma2   = (const float*)d_in[18];
    const float* beta2    = (const float*)d_in[19];
    const float* gamma3   = (const float*)d_in[20];
    const float* beta3    = (const float*)d_in[21];
    const float* pw1      = (const float*)d_in[22];
    const float* pw2      = (const float*)d_in[23];
    const float* pw3      = (const float*)d_in[24];
    const float* lin1_w   = (const float*)d_in[25];
    const float* lin1_b   = (const float*)d_in[26];
    const float* lin2_w   = (const float*)d_in[27];
    const float* lin2_b   = (const float*)d_in[28];

    const int* ei_src = ei;
    const int* ei_dst = ei + E_TOT;

    // Workspace carve (256B-aligned chunks)
    char* wp = (char*)d_ws;
    auto alloc = [&](size_t bytes) { char* p = wp; wp += (bytes + 255) & ~(size_t)255; return p; };
    float* h1     = (float*)alloc(4096 * 128 * 4);
    float* x2     = (float*)alloc(2048 * 128 * 4);
    float* h2     = (float*)alloc(2048 * 128 * 4);
    float* x3     = (float*)alloc(1024 * 128 * 4);
    float* h3     = (float*)alloc(1024 * 128 * 4);
    float* x4     = (float*)alloc(512 * 128 * 4);
    float* score1 = (float*)alloc(4096 * 4);
    float* score2 = (float*)alloc(2048 * 4);
    float* score3 = (float*)alloc(1024 * 4);
    int*   map1   = (int*)alloc(4096 * 4);
    int*   map2   = (int*)alloc(2048 * 4);
    int*   map3   = (int*)alloc(1024 * 4);
    int*   src1   = (int*)alloc(E_TOT * 4);
    int*   dst1   = (int*)alloc(E_TOT * 4);
    int*   src2   = (int*)alloc(E_TOT * 4);
    int*   dst2   = (int*)alloc(E_TOT * 4);
    float* stats  = (float*)alloc(6 * 128 * 4);
    float* invn   = (float*)alloc(16);

    // Y chunk buffer: adapt d-chunking to whatever workspace remains.
    const size_t base   = (size_t)(wp - (char*)d_ws);
    const size_t per_d  = (size_t)4096 * 128 * 4;  // 2 MB per d (max nodes)
    const size_t avail  = (ws_size > base) ? (ws_size - base) : 0;
    int nd_chunk = (int)(avail / per_d);
    if (nd_chunk < 1)  nd_chunk = 1;    // best effort
    if (nd_chunk > ND) nd_chunk = ND;
    float* Ybuf = (float*)alloc((size_t)nd_chunk * per_d);

    hipMemsetAsync(stats, 0, 6 * 128 * sizeof(float), stream);
    invnorm_kernel<<<1, 128, 0, stream>>>(pw1, pw2, pw3, invn);

    // ---- Stage 1: NNConv(64->128) + BN + ReLU + TopK(128->64) ----
    node_root<64><<<4096, 128, 0, stream>>>(x, root1, bias1, h1);
    for (int d0 = 0; d0 < ND; d0 += nd_chunk) {
        const int nd = (ND - d0 < nd_chunk) ? (ND - d0) : nd_chunk;
        ygemm<64><<<dim3(4096 / 128, nd), 256, 0, stream>>>(x, nn1_w, nn1_b, d0, Ybuf, nd);
        contract_edges<<<E_TOT / 4, 256, 0, stream>>>(Ybuf, eattr, ei_src, ei_dst, nd, d0, h1);
    }
    bn_stats<<<64, 256, 0, stream>>>(h1, 4096, stats, stats + 128);
    bn_apply_score<<<4096, 128, 0, stream>>>(h1, 4096.0f, stats, stats + 128,
                                             gamma1, beta1, pw1, invn, 0, score1);
    pool_kernel<<<NB, 128, 0, stream>>>(h1, score1, 128, 64, x2, map1);
    remap_edges<<<E_TOT / 256, 256, 0, stream>>>(ei_src, ei_dst, map1, src1, dst1);

    // ---- Stage 2: NNConv(128->128) + BN + ReLU + TopK(64->32) ----
    node_root<128><<<2048, 128, 0, stream>>>(x2, root2, bias2, h2);
    for (int d0 = 0; d0 < ND; d0 += nd_chunk) {
        const int nd = (ND - d0 < nd_chunk) ? (ND - d0) : nd_chunk;
        ygemm<128><<<dim3(2048 / 128, nd), 256, 0, stream>>>(x2, nn2_w, nn2_b, d0, Ybuf, nd);
        contract_edges<<<E_TOT / 4, 256, 0, stream>>>(Ybuf, eattr, src1, dst1, nd, d0, h2);
    }
    bn_stats<<<64, 256, 0, stream>>>(h2, 2048, stats + 256, stats + 384);
    bn_apply_score<<<2048, 128, 0, stream>>>(h2, 2048.0f, stats + 256, stats + 384,
                                             gamma2, beta2, pw2, invn, 1, score2);
    pool_kernel<<<NB, 128, 0, stream>>>(h2, score2, 64, 32, x3, map2);
    remap_edges<<<E_TOT / 256, 256, 0, stream>>>(src1, dst1, map2, src2, dst2);

    // ---- Stage 3: NNConv(128->128) + BN + ReLU + TopK(32->16) ----
    node_root<128><<<1024, 128, 0, stream>>>(x3, root3, bias3, h3);
    for (int d0 = 0; d0 < ND; d0 += nd_chunk) {
        const int nd = (ND - d0 < nd_chunk) ? (ND - d0) : nd_chunk;
        ygemm<128><<<dim3(1024 / 128, nd), 256, 0, stream>>>(x3, nn3_w, nn3_b, d0, Ybuf, nd);
        contract_edges<<<E_TOT / 4, 256, 0, stream>>>(Ybuf, eattr, src2, dst2, nd, d0, h3);
    }
    bn_stats<<<64, 256, 0, stream>>>(h3, 1024, stats + 512, stats + 640);
    bn_apply_score<<<1024, 128, 0, stream>>>(h3, 1024.0f, stats + 512, stats + 640,
                                             gamma3, beta3, pw3, invn, 2, score3);
    pool_kernel<<<NB, 128, 0, stream>>>(h3, score3, 32, 16, x4, map3);

    // ---- Readout ----
    final_kernel<<<NB, 128, 0, stream>>>(x4, lin1_w, lin1_b, lin2_w, lin2_b, (float*)d_out);
}

// Round 3
// 340.733 us; speedup vs baseline: 5.2335x; 1.3122x over previous
//
#include <hip/hip_runtime.h>

// Problem constants
#define E_TOT 8192
#define NB    32
#define H     128
#define NDT   34      // 32 edge-attr dims + 1 bias row + 1 root block

typedef __attribute__((ext_vector_type(8))) short bf16x8;
typedef __attribute__((ext_vector_type(4))) float f32x4;

__device__ __forceinline__ unsigned short bf16_rne(float f) {
    unsigned int u = __float_as_uint(f);
    unsigned int r = (u + 0x7FFFu + ((u >> 16) & 1u)) >> 16;
    return (unsigned short)r;
}
__device__ __forceinline__ float bf16_to_f32(unsigned short h) {
    return __uint_as_float(((unsigned int)h) << 16);
}

__device__ __forceinline__ void gload_lds16(const void* g, void* l) {
    __builtin_amdgcn_global_load_lds(
        (const __attribute__((address_space(1))) unsigned int*)g,
        (__attribute__((address_space(3))) unsigned int*)l, 16, 0, 0);
}

// ---------------------------------------------------------------------------
// build_A: A'[v, k'] = [xh | xh | xl] along k' (K'=3*CIN), bf16 bits.
// ---------------------------------------------------------------------------
template<int CIN>
__global__ __launch_bounds__(128)
void build_A(const float* __restrict__ x, unsigned short* __restrict__ A)
{
    const int v = blockIdx.x;
    unsigned short* row = A + (size_t)v * (3 * CIN);
    for (int i = threadIdx.x; i < CIN; i += 128) {
        const float val = x[(size_t)v * CIN + i];
        const unsigned short h = bf16_rne(val);
        const unsigned short l = bf16_rne(val - bf16_to_f32(h));
        row[i] = h; row[CIN + i] = h; row[2 * CIN + i] = l;
    }
}

// ---------------------------------------------------------------------------
// build_Bt: Bt[n, k'] with n = d*128+o (d<32: nn_w, d=32: nn_b, d=33: root),
// k' layout [wh ; wl ; wh]. LDS-transposed so writes are 16B vectors.
// Grid: (34, CIN/32), 256 threads.
// ---------------------------------------------------------------------------
template<int CIN>
__global__ __launch_bounds__(256)
void build_Bt(const float* __restrict__ nnw, const float* __restrict__ nnb,
              const float* __restrict__ root, unsigned short* __restrict__ Bt)
{
    const int d  = blockIdx.x;
    const int i0 = blockIdx.y * 32;
    const float* __restrict__ W =
        (d < 32) ? (nnw + (size_t)d * CIN * 128) : ((d == 32) ? nnb : root);

    __shared__ unsigned short LHI[128][40];   // [o][ii], 80B rows (16B-aligned)
    __shared__ unsigned short LLO[128][40];

    for (int idx = threadIdx.x; idx < 32 * 128; idx += 256) {
        const int ii = idx >> 7, o = idx & 127;
        const float val = W[(size_t)(i0 + ii) * 128 + o];
        const unsigned short h = bf16_rne(val);
        const unsigned short l = bf16_rne(val - bf16_to_f32(h));
        LHI[o][ii] = h; LLO[o][ii] = l;
    }
    __syncthreads();

    const int o    = threadIdx.x & 127;
    const int half = threadIdx.x >> 7;
    unsigned short* dst = Bt + (size_t)(d * 128 + o) * (3 * CIN);
    const uint4* hs = (const uint4*)&LHI[o][0];
    const uint4* ls = (const uint4*)&LLO[o][0];
    if (half == 0) {
        uint4* p = (uint4*)(dst + i0);
        p[0] = hs[0]; p[1] = hs[1]; p[2] = hs[2]; p[3] = hs[3];
        uint4* q = (uint4*)(dst + 2 * CIN + i0);
        q[0] = ls[0]; q[1] = ls[1]; q[2] = ls[2]; q[3] = ls[3];
    } else {
        uint4* p = (uint4*)(dst + CIN + i0);
        p[0] = hs[0]; p[1] = hs[1]; p[2] = hs[2]; p[3] = hs[3];
    }
}

// ---------------------------------------------------------------------------
// ygemm_mfma: Y[v0..v0+127, n0..n0+127] = A'[M,K3] @ Bt'[N,K3]^T  (bf16 MFMA)
// 128x128 tile, 4 waves in 2x2, each wave 64x64 via 4x4 16x16x32 frags.
// Staging via global_load_lds width=16, [row][32k] LDS layout.
// ---------------------------------------------------------------------------
template<int K3>
__global__ __launch_bounds__(256)
void ygemm_mfma(const unsigned short* __restrict__ A,   // [M, K3]
                const unsigned short* __restrict__ Bt,  // rows n (chunk-offset), [*, K3]
                float* __restrict__ Y, int ycols)       // Y row stride = ycols
{
    __shared__ unsigned short Alds[128 * 32];
    __shared__ unsigned short Blds[128 * 32];

    const int lane = threadIdx.x & 63;
    const int w    = threadIdx.x >> 6;
    const int wm = w >> 1, wn = w & 1;
    const int v0 = blockIdx.x * 128;
    const int n0 = blockIdx.y * 128;

    f32x4 acc[4][4];
    #pragma unroll
    for (int i = 0; i < 4; ++i)
        #pragma unroll
        for (int j = 0; j < 4; ++j)
            acc[i][j] = (f32x4)(0.0f);

    const int arow = lane >> 2;          // row within 16-row chunk
    const int acol = (lane & 3) * 8;     // shorts offset within 32-k row
    const int koff = (lane >> 4) * 8;    // frag k offset (quad*8)
    const int mrow = lane & 15;

    for (int k0 = 0; k0 < K3; k0 += 32) {
        __syncthreads();   // prior ds_reads done before overwrite
        #pragma unroll
        for (int t = 0; t < 2; ++t) {
            const int c = w * 2 + t;               // chunk 0..7 (16 rows each)
            const int r = c * 16 + arow;
            gload_lds16(A  + (size_t)(v0 + r) * K3 + k0 + acol, &Alds[c * 512]);
            gload_lds16(Bt + (size_t)(n0 + r) * K3 + k0 + acol, &Blds[c * 512]);
        }
        __syncthreads();   // drains vmcnt (global_load_lds) per barrier semantics

        bf16x8 a[4], b[4];
        #pragma unroll
        for (int f = 0; f < 4; ++f) {
            a[f] = *(const bf16x8*)&Alds[(wm * 64 + f * 16 + mrow) * 32 + koff];
            b[f] = *(const bf16x8*)&Blds[(wn * 64 + f * 16 + mrow) * 32 + koff];
        }
        #pragma unroll
        for (int fm = 0; fm < 4; ++fm)
            #pragma unroll
            for (int fn = 0; fn < 4; ++fn)
                acc[fm][fn] = __builtin_amdgcn_mfma_f32_16x16x32_bf16(
                    a[fm], b[fn], acc[fm][fn], 0, 0, 0);
    }

    const int crow = (lane >> 4) * 4;
    const int ccol = lane & 15;
    #pragma unroll
    for (int fm = 0; fm < 4; ++fm) {
        const int gr = v0 + wm * 64 + fm * 16 + crow;
        #pragma unroll
        for (int fn = 0; fn < 4; ++fn) {
            const int gc = n0 + wn * 64 + fn * 16 + ccol;
            #pragma unroll
            for (int r = 0; r < 4; ++r)
                Y[(size_t)(gr + r) * ycols + gc] = acc[fm][fn][r];
        }
    }
}

// ---------------------------------------------------------------------------
// contract_edges: agg[dst[e], :] += sum_{dd<nd_c} coef(d0+dd) * Y[src[e], dd, :]
// coef = ea[e,gd] for gd<32, 1.0 for gd==32. One wave per edge.
// ---------------------------------------------------------------------------
__global__ __launch_bounds__(256)
void contract_edges(const float* __restrict__ Y,    // [nv, stride_d, 128]
                    const float* __restrict__ ea,   // [E, 32]
                    const int*   __restrict__ esrc, // [E], -1 invalid
                    const int*   __restrict__ edst,
                    int stride_d, int nd_c, int d0,
                    float*       __restrict__ agg)  // [n, 128]
{
    const int wave = threadIdx.x >> 6;
    const int lane = threadIdx.x & 63;
    const int e = blockIdx.x * 4 + wave;
    const int s = esrc[e];
    if (s < 0) return;

    const float* ybase = Y + (size_t)s * stride_d * H + lane * 2;
    float ax = 0.f, ay = 0.f;
    for (int dd = 0; dd < nd_c; ++dd) {
        const int gd = d0 + dd;
        const float c = (gd < 32) ? ea[(size_t)e * 32 + gd] : 1.0f;
        const float2 y = *reinterpret_cast<const float2*>(ybase + (size_t)dd * H);
        ax += c * y.x;
        ay += c * y.y;
    }
    float* out = agg + (size_t)edst[e] * H + lane * 2;
    atomicAdd(out, ax);
    atomicAdd(out + 1, ay);
}

// h[v,o] = Y[v, doff, o] + bias[o]   (root block + conv bias init)
__global__ __launch_bounds__(128)
void init_h(const float* __restrict__ Y, int ycols, int doff,
            const float* __restrict__ bias, float* __restrict__ h)
{
    const int v = blockIdx.x, o = threadIdx.x;
    h[(size_t)v * H + o] = Y[(size_t)v * ycols + (size_t)doff * H + o] + bias[o];
}

// Column sums / sumsq over n rows, atomically accumulated into gsum/gsumsq.
__global__ __launch_bounds__(256)
void bn_stats(const float* __restrict__ h, int n,
              float* __restrict__ gsum, float* __restrict__ gsumsq)
{
    const int tid   = threadIdx.x;
    const int col   = tid & 127;
    const int rhalf = tid >> 7;
    float s = 0.f, sq = 0.f;
    for (int r = blockIdx.x * 2 + rhalf; r < n; r += gridDim.x * 2) {
        float v = h[(size_t)r * H + col];
        s += v; sq += v * v;
    }
    __shared__ float sh[256];
    sh[tid] = s;  __syncthreads();
    if (rhalf == 0) s += sh[tid + 128];
    __syncthreads();
    sh[tid] = sq; __syncthreads();
    if (rhalf == 0) {
        sq += sh[tid + 128];
        atomicAdd(&gsum[col], s);
        atomicAdd(&gsumsq[col], sq);
    }
}

// y = relu(gamma*(x-mu)*rsqrt(var+eps)+beta) in place; score[r]=tanh((y.pw)*invnorm)
__global__ __launch_bounds__(128)
void bn_apply_score(float* __restrict__ h, float n_f,
                    const float* __restrict__ gsum, const float* __restrict__ gsumsq,
                    const float* __restrict__ gamma, const float* __restrict__ beta,
                    const float* __restrict__ pw, const float* __restrict__ invn,
                    int invn_idx, float* __restrict__ score)
{
    const int r = blockIdx.x, c = threadIdx.x;
    const float mu  = gsum[c] / n_f;
    const float var = gsumsq[c] / n_f - mu * mu;
    float y = gamma[c] * (h[(size_t)r * H + c] - mu) * rsqrtf(var + 1e-5f) + beta[c];
    y = fmaxf(y, 0.f);
    h[(size_t)r * H + c] = y;
    __shared__ float sh[128];
    sh[c] = y * pw[c];
    __syncthreads();
    for (int off = 64; off > 0; off >>= 1) {
        if (c < off) sh[c] += sh[c + off];
        __syncthreads();
    }
    if (c == 0) score[r] = tanhf(sh[0] * invn[invn_idx]);
}

// invn[s] = 1/||pw_s||
__global__ __launch_bounds__(128)
void invnorm_kernel(const float* __restrict__ pw1, const float* __restrict__ pw2,
                    const float* __restrict__ pw3, float* __restrict__ invn)
{
    __shared__ float sh[128];
    const int tid = threadIdx.x;
    for (int s = 0; s < 3; ++s) {
        const float* pw = (s == 0) ? pw1 : ((s == 1) ? pw2 : pw3);
        float v = pw[tid];
        sh[tid] = v * v;
        __syncthreads();
        for (int off = 64; off > 0; off >>= 1) {
            if (tid < off) sh[tid] += sh[tid + off];
            __syncthreads();
        }
        if (tid == 0) invn[s] = rsqrtf(sh[0]);
        __syncthreads();
    }
}

// Per-graph top-k by rank; new id = rank (within-graph permutation is
// irrelevant downstream — BN/scatter/mean are row-permutation-invariant).
__global__ __launch_bounds__(128)
void pool_kernel(const float* __restrict__ h, const float* __restrict__ score,
                 int npg, int k, float* __restrict__ xnew, int* __restrict__ mapping)
{
    const int g = blockIdx.x;
    const int tid = threadIdx.x;
    __shared__ float s_ld[128];
    __shared__ int   rank_ld[128];
    if (tid < npg) s_ld[tid] = score[g * npg + tid];
    __syncthreads();
    if (tid < npg) {
        const float si = s_ld[tid];
        int cnt = 0;
        for (int j = 0; j < npg; ++j) {
            float sj = s_ld[j];
            cnt += (sj > si) || (sj == si && j < tid);
        }
        rank_ld[tid] = cnt;
        mapping[g * npg + tid] = (cnt < k) ? (g * k + cnt) : -1;
    }
    __syncthreads();
    for (int i = 0; i < npg; ++i) {
        const int r = rank_ld[i];
        if (r < k) {
            const float sc = s_ld[i];
            for (int c = tid; c < H; c += 128)
                xnew[(size_t)(g * k + r) * H + c] = h[(size_t)(g * npg + i) * H + c] * sc;
        }
    }
}

// Propagate edge endpoints through a pooling mapping; -1 marks invalid.
__global__ __launch_bounds__(256)
void remap_edges(const int* __restrict__ osrc, const int* __restrict__ odst,
                 const int* __restrict__ mapping,
                 int* __restrict__ nsrc, int* __restrict__ ndst)
{
    const int e = blockIdx.x * 256 + threadIdx.x;
    if (e >= E_TOT) return;
    const int s = osrc[e];
    int ns = -1, nd = -1;
    if (s >= 0) {
        int ms = mapping[s];
        int md = mapping[odst[e]];
        if (ms >= 0 && md >= 0) { ns = ms; nd = md; }
    }
    nsrc[e] = ns; ndst[e] = nd;
}

// mean over 16 rows -> lin1(128->64)+relu -> lin2(64->1)+sigmoid
__global__ __launch_bounds__(128)
void final_kernel(const float* __restrict__ x4,
                  const float* __restrict__ lin1_w, const float* __restrict__ lin1_b,
                  const float* __restrict__ lin2_w, const float* __restrict__ lin2_b,
                  float* __restrict__ out)
{
    const int g = blockIdx.x;
    const int tid = threadIdx.x;
    __shared__ float gmean[128];
    __shared__ float h1[64];
    float s = 0.f;
    for (int r = 0; r < 16; ++r) s += x4[(size_t)(g * 16 + r) * H + tid];
    gmean[tid] = s * (1.0f / 16.0f);
    __syncthreads();
    if (tid < 64) {
        float acc = lin1_b[tid];
        for (int o = 0; o < 128; ++o) acc += gmean[o] * lin1_w[o * 64 + tid];
        h1[tid] = fmaxf(acc, 0.f);
    }
    __syncthreads();
    if (tid == 0) {
        float z = lin2_b[0];
        for (int j = 0; j < 64; ++j) z += h1[j] * lin2_w[j];
        out[g] = 1.0f / (1.0f + expf(-z));
    }
}

extern "C" void kernel_launch(void* const* d_in, const int* in_sizes, int n_in,
                              void* d_out, int out_size, void* d_ws, size_t ws_size,
                              hipStream_t stream)
{
    const float* x        = (const float*)d_in[0];
    const int*   ei       = (const int*)  d_in[1];
    const float* eattr    = (const float*)d_in[2];
    const float* nn1_w    = (const float*)d_in[4];
    const float* nn1_b    = (const float*)d_in[5];
    const float* root1    = (const float*)d_in[6];
    const float* bias1    = (const float*)d_in[7];
    const float* nn2_w    = (const float*)d_in[8];
    const float* nn2_b    = (const float*)d_in[9];
    const float* root2    = (const float*)d_in[10];
    const float* bias2    = (const float*)d_in[11];
    const float* nn3_w    = (const float*)d_in[12];
    const float* nn3_b    = (const float*)d_in[13];
    const float* root3    = (const float*)d_in[14];
    const float* bias3    = (const float*)d_in[15];
    const float* gamma1   = (const float*)d_in[16];
    const float* beta1    = (const float*)d_in[17];
    const float* gamma2   = (const float*)d_in[18];
    const float* beta2    = (const float*)d_in[19];
    const float* gamma3   = (const float*)d_in[20];
    const float* beta3    = (const float*)d_in[21];
    const float* pw1      = (const float*)d_in[22];
    const float* pw2      = (const float*)d_in[23];
    const float* pw3      = (const float*)d_in[24];
    const float* lin1_w   = (const float*)d_in[25];
    const float* lin1_b   = (const float*)d_in[26];
    const float* lin2_w   = (const float*)d_in[27];
    const float* lin2_b   = (const float*)d_in[28];

    const int* ei_src = ei;
    const int* ei_dst = ei + E_TOT;

    char* wp = (char*)d_ws;
    auto alloc = [&](size_t bytes) { char* p = wp; wp += (bytes + 255) & ~(size_t)255; return p; };
    float* h1     = (float*)alloc(4096 * 128 * 4);
    float* x2     = (float*)alloc(2048 * 128 * 4);
    float* h2     = (float*)alloc(2048 * 128 * 4);
    float* x3     = (float*)alloc(1024 * 128 * 4);
    float* h3     = (float*)alloc(1024 * 128 * 4);
    float* x4     = (float*)alloc(512 * 128 * 4);
    float* score1 = (float*)alloc(4096 * 4);
    float* score2 = (float*)alloc(2048 * 4);
    float* score3 = (float*)alloc(1024 * 4);
    int*   map1   = (int*)alloc(4096 * 4);
    int*   map2   = (int*)alloc(2048 * 4);
    int*   map3   = (int*)alloc(1024 * 4);
    int*   src1   = (int*)alloc(E_TOT * 4);
    int*   dst1   = (int*)alloc(E_TOT * 4);
    int*   src2   = (int*)alloc(E_TOT * 4);
    int*   dst2   = (int*)alloc(E_TOT * 4);
    float* stats  = (float*)alloc(6 * 128 * 4);
    float* invn   = (float*)alloc(16);
    unsigned short* Abuf  = (unsigned short*)alloc((size_t)4096 * 192 * 2);  // max A'
    unsigned short* Btbuf = (unsigned short*)alloc((size_t)4352 * 384 * 2);  // max Bt'

    // Y chunk buffer sized from remaining workspace (2 MB per d-row @ 4096 nodes)
    const size_t base  = (size_t)(wp - (char*)d_ws);
    const size_t per_d = (size_t)4096 * 128 * 4;
    const size_t avail = (ws_size > base) ? (ws_size - base) : 0;
    int ndc = (int)(avail / per_d);
    if (ndc < 1)   ndc = 1;
    if (ndc > NDT) ndc = NDT;
    float* Ybuf = (float*)alloc((size_t)ndc * per_d);

    hipMemsetAsync(stats, 0, 6 * 128 * sizeof(float), stream);
    invnorm_kernel<<<1, 128, 0, stream>>>(pw1, pw2, pw3, invn);

    // Per-stage driver: chunks processed in REVERSE d-order so the chunk
    // containing d=33 (root) runs first -> init_h precedes all contract atomics.
    auto run_stage = [&](int M, int K3v, const float* bias,
                         const int* es, const int* ed, float* h)
    {
        const int nchunks = (NDT + ndc - 1) / ndc;
        for (int ci = nchunks - 1; ci >= 0; --ci) {
            const int d0 = ci * ndc;
            const int nd = (NDT - d0 < ndc) ? (NDT - d0) : ndc;
            const unsigned short* Btc = Btbuf + (size_t)d0 * 128 * K3v;
            if (K3v == 192)
                ygemm_mfma<192><<<dim3(M / 128, nd), 256, 0, stream>>>(Abuf, Btc, Ybuf, nd * 128);
            else
                ygemm_mfma<384><<<dim3(M / 128, nd), 256, 0, stream>>>(Abuf, Btc, Ybuf, nd * 128);
            if (d0 <= 33 && 33 < d0 + nd)
                init_h<<<M, 128, 0, stream>>>(Ybuf, nd * 128, 33 - d0, bias, h);
            const int nd_c = ((33 - d0) < nd) ? (33 - d0) : nd;   // conv d-rows in chunk
            if (nd_c > 0)
                contract_edges<<<E_TOT / 4, 256, 0, stream>>>(Ybuf, eattr, es, ed,
                                                              nd, nd_c, d0, h);
        }
    };

    // ---- Stage 1: NNConv(64->128) + BN + ReLU + TopK(128->64) ----
    build_A<64><<<4096, 128, 0, stream>>>(x, Abuf);
    build_Bt<64><<<dim3(NDT, 2), 256, 0, stream>>>(nn1_w, nn1_b, root1, Btbuf);
    run_stage(4096, 192, bias1, ei_src, ei_dst, h1);
    bn_stats<<<64, 256, 0, stream>>>(h1, 4096, stats, stats + 128);
    bn_apply_score<<<4096, 128, 0, stream>>>(h1, 4096.0f, stats, stats + 128,
                                             gamma1, beta1, pw1, invn, 0, score1);
    pool_kernel<<<NB, 128, 0, stream>>>(h1, score1, 128, 64, x2, map1);
    remap_edges<<<E_TOT / 256, 256, 0, stream>>>(ei_src, ei_dst, map1, src1, dst1);

    // ---- Stage 2: NNConv(128->128) + BN + ReLU + TopK(64->32) ----
    build_A<128><<<2048, 128, 0, stream>>>(x2, Abuf);
    build_Bt<128><<<dim3(NDT, 4), 256, 0, stream>>>(nn2_w, nn2_b, root2, Btbuf);
    run_stage(2048, 384, bias2, src1, dst1, h2);
    bn_stats<<<64, 256, 0, stream>>>(h2, 2048, stats + 256, stats + 384);
    bn_apply_score<<<2048, 128, 0, stream>>>(h2, 2048.0f, stats + 256, stats + 384,
                                             gamma2, beta2, pw2, invn, 1, score2);
    pool_kernel<<<NB, 128, 0, stream>>>(h2, score2, 64, 32, x3, map2);
    remap_edges<<<E_TOT / 256, 256, 0, stream>>>(src1, dst1, map2, src2, dst2);

    // ---- Stage 3: NNConv(128->128) + BN + ReLU + TopK(32->16) ----
    build_A<128><<<1024, 128, 0, stream>>>(x3, Abuf);
    build_Bt<128><<<dim3(NDT, 4), 256, 0, stream>>>(nn3_w, nn3_b, root3, Btbuf);
    run_stage(1024, 384, bias3, src2, dst2, h3);
    bn_stats<<<64, 256, 0, stream>>>(h3, 1024, stats + 512, stats + 640);
    bn_apply_score<<<1024, 128, 0, stream>>>(h3, 1024.0f, stats + 512, stats + 640,
                                             gamma3, beta3, pw3, invn, 2, score3);
    pool_kernel<<<NB, 128, 0, stream>>>(h3, score3, 32, 16, x4, map3);

    // ---- Readout ----
    final_kernel<<<NB, 128, 0, stream>>>(x4, lin1_w, lin1_b, lin2_w, lin2_b, (float*)d_out);
}

// Round 4
// 318.033 us; speedup vs baseline: 5.6070x; 1.0714x over previous
//
#include <hip/hip_runtime.h>

// Problem constants
#define E_TOT 8192
#define NB    32
#define H     128
#define EPG   256          // edges per graph (contiguous slots)
#define NDT   34           // 32 edge-attr dims + 1 bias row + 1 root block
#define YD    33           // Y keeps only d<33 (root fused into h)
#define YCOLS (YD * H)     // 4224

typedef __attribute__((ext_vector_type(8))) short bf16x8;
typedef __attribute__((ext_vector_type(4))) float f32x4;

__device__ __forceinline__ unsigned short bf16_rne(float f) {
    unsigned int u = __float_as_uint(f);
    unsigned int r = (u + 0x7FFFu + ((u >> 16) & 1u)) >> 16;
    return (unsigned short)r;
}
__device__ __forceinline__ float bf16_to_f32(unsigned short h) {
    return __uint_as_float(((unsigned int)h) << 16);
}

__device__ __forceinline__ void gload_lds16(const void* g, void* l) {
    __builtin_amdgcn_global_load_lds(
        (const __attribute__((address_space(1))) unsigned int*)g,
        (__attribute__((address_space(3))) unsigned int*)l, 16, 0, 0);
}

// ---------------------------------------------------------------------------
// build_A: A'[v, k'] = [xh | xh | xl] along k' (K'=3*CIN), bf16 bits.
// Stage-1 only (stages 2/3 get A' from fused_pool).
// ---------------------------------------------------------------------------
template<int CIN>
__global__ __launch_bounds__(128)
void build_A(const float* __restrict__ x, unsigned short* __restrict__ A)
{
    const int v = blockIdx.x;
    unsigned short* row = A + (size_t)v * (3 * CIN);
    for (int i = threadIdx.x; i < CIN; i += 128) {
        const float val = x[(size_t)v * CIN + i];
        const unsigned short h = bf16_rne(val);
        const unsigned short l = bf16_rne(val - bf16_to_f32(h));
        row[i] = h; row[CIN + i] = h; row[2 * CIN + i] = l;
    }
}

// ---------------------------------------------------------------------------
// build_Bt: Bt[n, k'] with n = d*128+o (d<32: nn_w, d=32: nn_b, d=33: root),
// k' layout [wh ; wl ; wh]. LDS-transposed so writes are 16B vectors.
// Grid: (34, CIN/32), 256 threads. Weight-only: all 3 stages run up front.
// ---------------------------------------------------------------------------
template<int CIN>
__global__ __launch_bounds__(256)
void build_Bt(const float* __restrict__ nnw, const float* __restrict__ nnb,
              const float* __restrict__ root, unsigned short* __restrict__ Bt)
{
    const int d  = blockIdx.x;
    const int i0 = blockIdx.y * 32;
    const float* __restrict__ W =
        (d < 32) ? (nnw + (size_t)d * CIN * 128) : ((d == 32) ? nnb : root);

    __shared__ unsigned short LHI[128][40];
    __shared__ unsigned short LLO[128][40];

    for (int idx = threadIdx.x; idx < 32 * 128; idx += 256) {
        const int ii = idx >> 7, o = idx & 127;
        const float val = W[(size_t)(i0 + ii) * 128 + o];
        const unsigned short h = bf16_rne(val);
        const unsigned short l = bf16_rne(val - bf16_to_f32(h));
        LHI[o][ii] = h; LLO[o][ii] = l;
    }
    __syncthreads();

    const int o    = threadIdx.x & 127;
    const int half = threadIdx.x >> 7;
    unsigned short* dst = Bt + (size_t)(d * 128 + o) * (3 * CIN);
    const uint4* hs = (const uint4*)&LHI[o][0];
    const uint4* ls = (const uint4*)&LLO[o][0];
    if (half == 0) {
        uint4* p = (uint4*)(dst + i0);
        p[0] = hs[0]; p[1] = hs[1]; p[2] = hs[2]; p[3] = hs[3];
        uint4* q = (uint4*)(dst + 2 * CIN + i0);
        q[0] = ls[0]; q[1] = ls[1]; q[2] = ls[2]; q[3] = ls[3];
    } else {
        uint4* p = (uint4*)(dst + CIN + i0);
        p[0] = hs[0]; p[1] = hs[1]; p[2] = hs[2]; p[3] = hs[3];
    }
}

// ---------------------------------------------------------------------------
// ygemm_mfma: 128x128 bf16-MFMA tile of A'[M,K3] @ Bt'[N,K3]^T.
// blockIdx.y < 33: writes Y[:, d, :].  blockIdx.y == 33 (root block):
// writes h[:, :] = acc + bias directly (init_h fused).
// ---------------------------------------------------------------------------
template<int K3>
__global__ __launch_bounds__(256)
void ygemm_mfma(const unsigned short* __restrict__ A,
                const unsigned short* __restrict__ Bt,
                float* __restrict__ Y,
                const float* __restrict__ bias,
                float* __restrict__ h)
{
    __shared__ unsigned short Alds[128 * 32];
    __shared__ unsigned short Blds[128 * 32];

    const int lane = threadIdx.x & 63;
    const int w    = threadIdx.x >> 6;
    const int wm = w >> 1, wn = w & 1;
    const int v0 = blockIdx.x * 128;
    const int n0 = blockIdx.y * 128;

    f32x4 acc[4][4];
    #pragma unroll
    for (int i = 0; i < 4; ++i)
        #pragma unroll
        for (int j = 0; j < 4; ++j)
            acc[i][j] = (f32x4)(0.0f);

    const int arow = lane >> 2;
    const int acol = (lane & 3) * 8;
    const int koff = (lane >> 4) * 8;
    const int mrow = lane & 15;

    for (int k0 = 0; k0 < K3; k0 += 32) {
        __syncthreads();
        #pragma unroll
        for (int t = 0; t < 2; ++t) {
            const int c = w * 2 + t;
            const int r = c * 16 + arow;
            gload_lds16(A  + (size_t)(v0 + r) * K3 + k0 + acol, &Alds[c * 512]);
            gload_lds16(Bt + (size_t)(n0 + r) * K3 + k0 + acol, &Blds[c * 512]);
        }
        __syncthreads();

        bf16x8 a[4], b[4];
        #pragma unroll
        for (int f = 0; f < 4; ++f) {
            a[f] = *(const bf16x8*)&Alds[(wm * 64 + f * 16 + mrow) * 32 + koff];
            b[f] = *(const bf16x8*)&Blds[(wn * 64 + f * 16 + mrow) * 32 + koff];
        }
        #pragma unroll
        for (int fm = 0; fm < 4; ++fm)
            #pragma unroll
            for (int fn = 0; fn < 4; ++fn)
                acc[fm][fn] = __builtin_amdgcn_mfma_f32_16x16x32_bf16(
                    a[fm], b[fn], acc[fm][fn], 0, 0, 0);
    }

    const int crow = (lane >> 4) * 4;
    const int ccol = lane & 15;
    const bool is_root = (blockIdx.y == YD);
    #pragma unroll
    for (int fm = 0; fm < 4; ++fm) {
        const int gr = v0 + wm * 64 + fm * 16 + crow;
        #pragma unroll
        for (int fn = 0; fn < 4; ++fn) {
            const int col = wn * 64 + fn * 16 + ccol;   // 0..127 within d-block
            if (is_root) {
                const float bv = bias[col];
                #pragma unroll
                for (int r = 0; r < 4; ++r)
                    h[(size_t)(gr + r) * H + col] = acc[fm][fn][r] + bv;
            } else {
                const size_t gc = (size_t)blockIdx.y * H + col;
                #pragma unroll
                for (int r = 0; r < 4; ++r)
                    Y[(size_t)(gr + r) * YCOLS + gc] = acc[fm][fn][r];
            }
        }
    }
}

// ---------------------------------------------------------------------------
// contract_edges: h[dst[e], :] += sum_{d<32} ea[e,d]*Y[src[e],d,:] + Y[src[e],32,:]
// One 32-lane group per edge, float4 per lane (512B coalesced rows).
// ---------------------------------------------------------------------------
__global__ __launch_bounds__(256)
void contract_edges(const float* __restrict__ Y,
                    const float* __restrict__ ea,
                    const int*   __restrict__ esrc,
                    const int*   __restrict__ edst,
                    float*       __restrict__ agg)
{
    const int grp = threadIdx.x >> 5;          // 8 groups per block
    const int l5  = threadIdx.x & 31;
    const int e   = blockIdx.x * 8 + grp;
    const int s   = esrc[e];
    if (s < 0) return;

    const float* yb  = Y + (size_t)s * YCOLS + l5 * 4;
    const float* ear = ea + (size_t)e * 32;

    float4 acc = *reinterpret_cast<const float4*>(yb + 32 * H);   // bias row, coef 1
    #pragma unroll 8
    for (int dd = 0; dd < 32; ++dd) {
        const float c = ear[dd];
        const float4 y = *reinterpret_cast<const float4*>(yb + dd * H);
        acc.x += c * y.x; acc.y += c * y.y; acc.z += c * y.z; acc.w += c * y.w;
    }
    float* out = agg + (size_t)edst[e] * H + l5 * 4;
    atomicAdd(out + 0, acc.x);
    atomicAdd(out + 1, acc.y);
    atomicAdd(out + 2, acc.z);
    atomicAdd(out + 3, acc.w);
}

// Column sums / sumsq over n rows of raw h, atomically accumulated.
__global__ __launch_bounds__(256)
void bn_stats(const float* __restrict__ h, int n,
              float* __restrict__ gsum, float* __restrict__ gsumsq)
{
    const int tid   = threadIdx.x;
    const int col   = tid & 127;
    const int rhalf = tid >> 7;
    float s = 0.f, sq = 0.f;
    for (int r = blockIdx.x * 2 + rhalf; r < n; r += gridDim.x * 2) {
        float v = h[(size_t)r * H + col];
        s += v; sq += v * v;
    }
    __shared__ float sh[256];
    sh[tid] = s;  __syncthreads();
    if (rhalf == 0) s += sh[tid + 128];
    __syncthreads();
    sh[tid] = sq; __syncthreads();
    if (rhalf == 0) {
        sq += sh[tid + 128];
        atomicAdd(&gsum[col], s);
        atomicAdd(&gsumsq[col], sq);
    }
}

// ---------------------------------------------------------------------------
// fused_pool: one block per graph. BN(on-the-fly from raw h) + ReLU + score +
// top-k rank + next-stage split-bf16 A' emission + edge remap.
// Block: 256 threads (4 waves). npg<=128, k<=64.
// ---------------------------------------------------------------------------
__global__ __launch_bounds__(256)
void fused_pool(const float* __restrict__ h,
                const float* __restrict__ gsum, const float* __restrict__ gsumsq,
                float n_f,
                const float* __restrict__ gamma, const float* __restrict__ beta,
                const float* __restrict__ pw,
                int npg, int k,
                const int* __restrict__ esrc_in, const int* __restrict__ edst_in,
                int* __restrict__ esrc_out, int* __restrict__ edst_out,
                unsigned short* __restrict__ Aout)   // [NB*k, 384]
{
    const int g   = blockIdx.x;
    const int tid = threadIdx.x;
    const int wv  = tid >> 6;
    const int ln  = tid & 63;

    __shared__ float muL[128], rsL[128], gmL[128], btL[128], pwL[128];
    __shared__ float scoreL[128], red[128];
    __shared__ int   mapL[128];
    __shared__ float sinv;

    if (tid < 128) {
        const float mu  = gsum[tid] / n_f;
        const float var = gsumsq[tid] / n_f - mu * mu;
        muL[tid] = mu;
        rsL[tid] = rsqrtf(var + 1e-5f);
        gmL[tid] = gamma[tid];
        btL[tid] = beta[tid];
        const float p = pw[tid];
        pwL[tid] = p;
        red[tid] = p * p;
    }
    __syncthreads();
    for (int off = 64; off > 0; off >>= 1) {
        if (tid < off) red[tid] += red[tid + off];
        __syncthreads();
    }
    if (tid == 0) sinv = rsqrtf(red[0]);
    __syncthreads();

    // ---- scores: one wave per row ----
    for (int r = wv; r < npg; r += 4) {
        const float* hr = h + (size_t)(g * npg + r) * H;
        float p = 0.f;
        #pragma unroll
        for (int half = 0; half < 2; ++half) {
            const int c = ln + half * 64;
            const float y = fmaxf(gmL[c] * (hr[c] - muL[c]) * rsL[c] + btL[c], 0.f);
            p += y * pwL[c];
        }
        #pragma unroll
        for (int off = 32; off > 0; off >>= 1)
            p += __shfl_down(p, off, 64);
        if (ln == 0) scoreL[r] = tanhf(p * sinv);
    }
    __syncthreads();

    // ---- rank / mapping ----
    if (tid < npg) {
        const float si = scoreL[tid];
        int cnt = 0;
        for (int j = 0; j < npg; ++j) {
            const float sj = scoreL[j];
            cnt += (sj > si) || (sj == si && j < tid);
        }
        mapL[tid] = (cnt < k) ? cnt : -1;
    }
    __syncthreads();

    // ---- emit next-stage A' rows (split bf16: [yh | yh | yl], K3=384) ----
    for (int r = wv; r < npg; r += 4) {
        const int nr = mapL[r];
        if (nr < 0) continue;
        const float sc = scoreL[r];
        const float* hr = h + (size_t)(g * npg + r) * H;
        unsigned short* arow = Aout + (size_t)(g * k + nr) * 384;
        #pragma unroll
        for (int half = 0; half < 2; ++half) {
            const int c = ln + half * 64;
            const float y = fmaxf(gmL[c] * (hr[c] - muL[c]) * rsL[c] + btL[c], 0.f) * sc;
            const unsigned short hb = bf16_rne(y);
            const unsigned short lb = bf16_rne(y - bf16_to_f32(hb));
            arow[c] = hb; arow[128 + c] = hb; arow[256 + c] = lb;
        }
    }

    // ---- remap this graph's 256 edges ----
    {
        const int e = g * EPG + tid;   // tid in [0,256)
        const int s = esrc_in[e];
        int ns = -1, nd = -1;
        if (s >= 0) {
            const int ms = mapL[s - g * npg];
            const int md = mapL[edst_in[e] - g * npg];
            if (ms >= 0 && md >= 0) { ns = g * k + ms; nd = g * k + md; }
        }
        esrc_out[e] = ns; edst_out[e] = nd;
    }
}

// ---------------------------------------------------------------------------
// fused_pool_final: stage-3 pool (npg=32,k=16) + mean-pool + MLP + sigmoid.
// ---------------------------------------------------------------------------
__global__ __launch_bounds__(256)
void fused_pool_final(const float* __restrict__ h,
                      const float* __restrict__ gsum, const float* __restrict__ gsumsq,
                      float n_f,
                      const float* __restrict__ gamma, const float* __restrict__ beta,
                      const float* __restrict__ pw,
                      const float* __restrict__ lin1_w, const float* __restrict__ lin1_b,
                      const float* __restrict__ lin2_w, const float* __restrict__ lin2_b,
                      float* __restrict__ out)
{
    const int g   = blockIdx.x;
    const int tid = threadIdx.x;
    const int wv  = tid >> 6;
    const int ln  = tid & 63;
    const int npg = 32, k = 16;

    __shared__ float muL[128], rsL[128], gmL[128], btL[128], pwL[128];
    __shared__ float scoreL[32], red[128], gmean[128], h1c[64];
    __shared__ int   mapL[32];
    __shared__ float sinv;

    if (tid < 128) {
        const float mu  = gsum[tid] / n_f;
        const float var = gsumsq[tid] / n_f - mu * mu;
        muL[tid] = mu;
        rsL[tid] = rsqrtf(var + 1e-5f);
        gmL[tid] = gamma[tid];
        btL[tid] = beta[tid];
        const float p = pw[tid];
        pwL[tid] = p;
        red[tid] = p * p;
    }
    __syncthreads();
    for (int off = 64; off > 0; off >>= 1) {
        if (tid < off) red[tid] += red[tid + off];
        __syncthreads();
    }
    if (tid == 0) sinv = rsqrtf(red[0]);
    __syncthreads();

    for (int r = wv; r < npg; r += 4) {
        const float* hr = h + (size_t)(g * npg + r) * H;
        float p = 0.f;
        #pragma unroll
        for (int half = 0; half < 2; ++half) {
            const int c = ln + half * 64;
            const float y = fmaxf(gmL[c] * (hr[c] - muL[c]) * rsL[c] + btL[c], 0.f);
            p += y * pwL[c];
        }
        #pragma unroll
        for (int off = 32; off > 0; off >>= 1)
            p += __shfl_down(p, off, 64);
        if (ln == 0) scoreL[r] = tanhf(p * sinv);
    }
    __syncthreads();

    if (tid < npg) {
        const float si = scoreL[tid];
        int cnt = 0;
        for (int j = 0; j < npg; ++j) {
            const float sj = scoreL[j];
            cnt += (sj > si) || (sj == si && j < tid);
        }
        mapL[tid] = (cnt < k) ? cnt : -1;
    }
    __syncthreads();

    // mean over kept rows of y*score
    if (tid < 128) {
        float acc = 0.f;
        for (int r = 0; r < npg; ++r) {
            if (mapL[r] < 0) continue;
            const float hv = h[(size_t)(g * npg + r) * H + tid];
            const float y  = fmaxf(gmL[tid] * (hv - muL[tid]) * rsL[tid] + btL[tid], 0.f);
            acc += y * scoreL[r];
        }
        gmean[tid] = acc * (1.0f / 16.0f);
    }
    __syncthreads();

    if (tid < 64) {
        float acc = lin1_b[tid];
        for (int o = 0; o < 128; ++o) acc += gmean[o] * lin1_w[o * 64 + tid];
        h1c[tid] = fmaxf(acc, 0.f);
    }
    __syncthreads();
    if (tid == 0) {
        float z = lin2_b[0];
        for (int j = 0; j < 64; ++j) z += h1c[j] * lin2_w[j];
        out[g] = 1.0f / (1.0f + expf(-z));
    }
}

extern "C" void kernel_launch(void* const* d_in, const int* in_sizes, int n_in,
                              void* d_out, int out_size, void* d_ws, size_t ws_size,
                              hipStream_t stream)
{
    const float* x        = (const float*)d_in[0];
    const int*   ei       = (const int*)  d_in[1];
    const float* eattr    = (const float*)d_in[2];
    const float* nn1_w    = (const float*)d_in[4];
    const float* nn1_b    = (const float*)d_in[5];
    const float* root1    = (const float*)d_in[6];
    const float* bias1    = (const float*)d_in[7];
    const float* nn2_w    = (const float*)d_in[8];
    const float* nn2_b    = (const float*)d_in[9];
    const float* root2    = (const float*)d_in[10];
    const float* bias2    = (const float*)d_in[11];
    const float* nn3_w    = (const float*)d_in[12];
    const float* nn3_b    = (const float*)d_in[13];
    const float* root3    = (const float*)d_in[14];
    const float* bias3    = (const float*)d_in[15];
    const float* gamma1   = (const float*)d_in[16];
    const float* beta1    = (const float*)d_in[17];
    const float* gamma2   = (const float*)d_in[18];
    const float* beta2    = (const float*)d_in[19];
    const float* gamma3   = (const float*)d_in[20];
    const float* beta3    = (const float*)d_in[21];
    const float* pw1      = (const float*)d_in[22];
    const float* pw2      = (const float*)d_in[23];
    const float* pw3      = (const float*)d_in[24];
    const float* lin1_w   = (const float*)d_in[25];
    const float* lin1_b   = (const float*)d_in[26];
    const float* lin2_w   = (const float*)d_in[27];
    const float* lin2_b   = (const float*)d_in[28];

    const int* ei_src = ei;
    const int* ei_dst = ei + E_TOT;

    char* wp = (char*)d_ws;
    auto alloc = [&](size_t bytes) { char* p = wp; wp += (bytes + 255) & ~(size_t)255; return p; };
    float* h1   = (float*)alloc(4096 * 128 * 4);
    float* h2   = (float*)alloc(2048 * 128 * 4);
    float* h3   = (float*)alloc(1024 * 128 * 4);
    int*   src1 = (int*)alloc(E_TOT * 4);
    int*   dst1 = (int*)alloc(E_TOT * 4);
    int*   src2 = (int*)alloc(E_TOT * 4);
    int*   dst2 = (int*)alloc(E_TOT * 4);
    float* stats = (float*)alloc(6 * 128 * 4);
    unsigned short* A1  = (unsigned short*)alloc((size_t)4096 * 192 * 2);
    unsigned short* A2  = (unsigned short*)alloc((size_t)2048 * 384 * 2);
    unsigned short* A3  = (unsigned short*)alloc((size_t)1024 * 384 * 2);
    unsigned short* Bt1 = (unsigned short*)alloc((size_t)4352 * 192 * 2);
    unsigned short* Bt2 = (unsigned short*)alloc((size_t)4352 * 384 * 2);
    unsigned short* Bt3 = (unsigned short*)alloc((size_t)4352 * 384 * 2);
    float* Ybuf = (float*)alloc((size_t)4096 * YCOLS * 4);   // 69 MB

    hipMemsetAsync(stats, 0, 6 * 128 * sizeof(float), stream);

    // Weight preprocessing (input-independent within the launch)
    build_Bt<64> <<<dim3(NDT, 2), 256, 0, stream>>>(nn1_w, nn1_b, root1, Bt1);
    build_Bt<128><<<dim3(NDT, 4), 256, 0, stream>>>(nn2_w, nn2_b, root2, Bt2);
    build_Bt<128><<<dim3(NDT, 4), 256, 0, stream>>>(nn3_w, nn3_b, root3, Bt3);
    build_A<64><<<4096, 128, 0, stream>>>(x, A1);

    // ---- Stage 1 ----
    ygemm_mfma<192><<<dim3(32, NDT), 256, 0, stream>>>(A1, Bt1, Ybuf, bias1, h1);
    contract_edges<<<E_TOT / 8, 256, 0, stream>>>(Ybuf, eattr, ei_src, ei_dst, h1);
    bn_stats<<<64, 256, 0, stream>>>(h1, 4096, stats, stats + 128);
    fused_pool<<<NB, 256, 0, stream>>>(h1, stats, stats + 128, 4096.0f,
                                       gamma1, beta1, pw1, 128, 64,
                                       ei_src, ei_dst, src1, dst1, A2);

    // ---- Stage 2 ----
    ygemm_mfma<384><<<dim3(16, NDT), 256, 0, stream>>>(A2, Bt2, Ybuf, bias2, h2);
    contract_edges<<<E_TOT / 8, 256, 0, stream>>>(Ybuf, eattr, src1, dst1, h2);
    bn_stats<<<64, 256, 0, stream>>>(h2, 2048, stats + 256, stats + 384);
    fused_pool<<<NB, 256, 0, stream>>>(h2, stats + 256, stats + 384, 2048.0f,
                                       gamma2, beta2, pw2, 64, 32,
                                       src1, dst1, src2, dst2, A3);

    // ---- Stage 3 ----
    ygemm_mfma<384><<<dim3(8, NDT), 256, 0, stream>>>(A3, Bt3, Ybuf, bias3, h3);
    contract_edges<<<E_TOT / 8, 256, 0, stream>>>(Ybuf, eattr, src2, dst2, h3);
    bn_stats<<<64, 256, 0, stream>>>(h3, 1024, stats + 512, stats + 640);
    fused_pool_final<<<NB, 256, 0, stream>>>(h3, stats + 512, stats + 640, 1024.0f,
                                             gamma3, beta3, pw3,
                                             lin1_w, lin1_b, lin2_w, lin2_b,
                                             (float*)d_out);
}